// Round 14
// baseline (25.782 us; speedup 1.0000x reference)
//
#include <hip/hip_runtime.h>
#include <hip/hip_bf16.h>
#include <stdint.h>

// Problem constants (fixed by reference)
#define N_STEPS 1000
#define NIN     2048
#define NHID    8192
#define M_PAD   1024

// LIF: TAU_REF/DT = 2000 > N_STEPS -> each neuron fires AT MOST ONCE; before
// first fire the recurrence is linear:
//   fire at first t with G(t) > 0.02*e^{5e-5 t}, G(t)=sum_{u<=t} c(u)e^{5e-5 u}
// At t=0: fire iff cur(0) > 0.02. For this data cur1(0) ~ 100 >> 0.02, so ALL
// hidden neurons fire at t=0 (flag==0). Then S1 = e_0 (x) ones, layer 2
// collapses to a column-sum of W2, and (G2 constant, threshold rising) the
// output fires at t=0 or never -> out rows 1..999 are all zero.
//
// R10 lesson: heterogeneous jobs on DIFFERENT blocks.
// R12 lesson: no grid barriers on the BW-bound live path.
// R13 lesson: ballot-mask + 4-deep ILP kills the rowvec latency chain.
// R14: colsum spread over 512 blocks (2/CU) so the 64 MiB pole saturates BW.
#define LIF_DINV   1.0000500012500208f   // e^{+DT/TAU_MEM}
#define LIF_LAM    5.0e-5f               // DT/TAU_MEM
#define LIF_THRG   0.02f                 // THR/SCALE

#define SEGS    64
#define SEGLEN  16
#define WQ      127.0f   // W1 i8 quant scale (fallback GEMM)
#define ISLICES 16       // rowvec i-slices (128 input rows each)
#define NBLK    512      // mega grid (2 blocks/CU on 256 CUs -> co-resident)

typedef short  bf16x8 __attribute__((ext_vector_type(8)));
typedef float  f32x4  __attribute__((ext_vector_type(4)));
typedef int    i32x4  __attribute__((ext_vector_type(4)));

typedef const __attribute__((address_space(1))) void gvoid_t;
typedef       __attribute__((address_space(3))) void lvoid_t;

__device__ __forceinline__ void gl_lds16(const void* g, void* l) {
    __builtin_amdgcn_global_load_lds((gvoid_t*)g, (lvoid_t*)l, 16, 0, 0);
}

// device-scope grid barrier (fallback path only; 512 blocks co-resident by
// __launch_bounds__(256,2) x 256 CUs)
__device__ __forceinline__ void gsync(int* cnt, int* gen) {
    __syncthreads();
    if (threadIdx.x == 0) {
        __threadfence();
        int g = __hip_atomic_load(gen, __ATOMIC_RELAXED, __HIP_MEMORY_SCOPE_AGENT);
        int a = __hip_atomic_fetch_add(cnt, 1, __ATOMIC_ACQ_REL, __HIP_MEMORY_SCOPE_AGENT);
        if (a == NBLK - 1) {
            __hip_atomic_store(cnt, 0, __ATOMIC_RELAXED, __HIP_MEMORY_SCOPE_AGENT);
            __hip_atomic_fetch_add(gen, 1, __ATOMIC_RELEASE, __HIP_MEMORY_SCOPE_AGENT);
        } else {
            while (__hip_atomic_load(gen, __ATOMIC_ACQUIRE, __HIP_MEMORY_SCOPE_AGENT) == g)
                __builtin_amdgcn_s_sleep(8);
        }
        __threadfence();
    }
    __syncthreads();
}

// ========================== LIVE PATH =======================================

// front (1280 blocks) — heterogeneous jobs on DIFFERENT blocks:
//   blocks    0..511 : PART[slice][i] = sum of 32 W2 rows (colsum, 2 blk/CU)
//   blocks 512..1023 : PS[is][j] = sum_{i active in slice} W1[i][j]
//                      (ballot mask + 4-deep ILP bit-scan)
//   blocks 1024..1279: out rows 1..999 = 0
//   block 0 thread 0 : init flag + barrier state (replay-safe)
__global__ void front(const float* __restrict__ x, const float* __restrict__ W1,
                      const float* __restrict__ W2,
                      float* __restrict__ PART, float* __restrict__ PS,
                      float* __restrict__ out, int* __restrict__ flag,
                      int* __restrict__ bar) {
    const int bid = blockIdx.x;
    const int tid = threadIdx.x;
    if (bid == 0 && tid == 0) { *flag = 0; bar[0] = 0; bar[1] = 0; }
    if (bid < 512) {
        const int slice = bid >> 1;                       // 0..255, 32 rows each
        const int col4  = ((bid & 1) * 256 + tid) * 4;
        const float* base = W2 + (size_t)slice * 32 * NIN + col4;
        f32x4 s = (f32x4){0.f, 0.f, 0.f, 0.f};
#pragma unroll 16
        for (int u = 0; u < 32; ++u)
            s += *(const f32x4*)(base + (size_t)u * NIN);  // 1KB/wave, deep ILP
        *(f32x4*)(PART + (size_t)slice * NIN + col4) = s;
    } else if (bid < 1024) {
        const int rb   = bid - 512;
        const int jc   = rb & 31;                          // 32 j-chunks
        const int is   = rb >> 5;                          // 16 i-slices
        const int j    = jc * 256 + tid;
        const int lane = tid & 63;
        const int ib   = is * 128;
        // wave-uniform 128-bit activity mask (two coalesced 256B x-reads)
        uint64_t m0 = __ballot(x[ib + lane] > 0.5f);        // rows ib..ib+63
        uint64_t m1 = __ballot(x[ib + 64 + lane] > 0.5f);   // rows +64..+127
        float s0 = 0.f, s1 = 0.f, s2 = 0.f, s3 = 0.f;
#pragma unroll 1
        for (int half = 0; half < 2; ++half) {
            uint64_t m   = half ? m1 : m0;
            const int rb0 = ib + half * 64;
#pragma unroll 1
            while (m) {
                int r0 = __ffsll((unsigned long long)m) - 1; m &= m - 1;
                int r1 = -1, r2 = -1, r3 = -1;
                if (m) { r1 = __ffsll((unsigned long long)m) - 1; m &= m - 1; }
                if (m) { r2 = __ffsll((unsigned long long)m) - 1; m &= m - 1; }
                if (m) { r3 = __ffsll((unsigned long long)m) - 1; m &= m - 1; }
                // 4 independent coalesced row loads in flight
                s0 += W1[(size_t)(rb0 + r0) * NHID + j];
                if (r1 >= 0) s1 += W1[(size_t)(rb0 + r1) * NHID + j];
                if (r2 >= 0) s2 += W1[(size_t)(rb0 + r2) * NHID + j];
                if (r3 >= 0) s3 += W1[(size_t)(rb0 + r3) * NHID + j];
            }
        }
        PS[(size_t)is * NHID + j] = (s0 + s1) + (s2 + s3);
    } else {
        const int zb = bid - 1024;                         // 0..255
#pragma unroll
        for (int k = 0; k < 8; ++k) {
            int job = zb * 256 + tid + k * 65536;          // rows 1..999
            if (job < 999 * 512) {
                int row  = 1 + (job >> 9);
                int col4 = (job & 511) * 4;
                *(f32x4*)(out + (size_t)row * NIN + col4) = (f32x4){0.f, 0.f, 0.f, 0.f};
            }
        }
    }
}

// tail (64 blocks):
//   blocks  0..31: decide — t1[j] = 0 if fired at t=0 else INT_MAX; flag
//   blocks 32..63: out[0][i] = (colsum W2 > 0.02) speculatively (mega, which
//                  runs after, rewrites the full output whenever flag != 0)
__global__ void tail(const float* __restrict__ PS, const float* __restrict__ PART,
                     int* __restrict__ t1, int* __restrict__ flag,
                     float* __restrict__ out) {
    const int bid = blockIdx.x;
    const int tid = threadIdx.x;
    if (bid < 32) {
        int j = bid * 256 + tid;
        float s = 0.f;
#pragma unroll
        for (int u = 0; u < ISLICES; ++u) s += PS[(size_t)u * NHID + j];
        bool fire = s > LIF_THRG;
        t1[j] = fire ? 0 : 0x7FFFFFFF;
        if (!fire) *flag = 1;    // benign race, same value
    } else {
        __shared__ float red[4][64];
        const int lc   = tid & 63;
        const int part = tid >> 6;                          // 0..3
        const int col  = (bid - 32) * 64 + lc;              // 32 blocks x 64 cols
        float s = 0.f;
#pragma unroll 8
        for (int u = 0; u < 64; ++u)
            s += PART[(size_t)(part * 64 + u) * NIN + col]; // 256 slices, L2-hot
        red[part][lc] = s;
        __syncthreads();
        if (tid < 64) {
            float tot = red[0][lc] + red[1][lc] + red[2][lc] + red[3][lc];
            out[col] = (tot > LIF_THRG) ? 1.0f : 0.0f;
        }
    }
}

// ================= GATED FALLBACK: ONE KERNEL, GRID-BARRIER =================
// Dead under bench data (flag==0 -> return before any barrier). Generic path:
// prep -> gemm -> seg_cross/zero -> gather -> out_scan -> write full out.
__launch_bounds__(256, 2)
__global__ void mega(const float* __restrict__ x, const float* __restrict__ W1,
                     const float* __restrict__ W2,
                     int8_t* __restrict__ Xi, int8_t* __restrict__ W1t,
                     __hip_bfloat16* __restrict__ CUR1, float* __restrict__ Ph,
                     float* __restrict__ CUR2, int* __restrict__ t1,
                     int* __restrict__ t2, float* __restrict__ out,
                     const int* __restrict__ flag, int* __restrict__ bar) {
    if (*flag == 0) return;
    const int b   = blockIdx.x;     // 0..511
    const int tid = threadIdx.x;
    int* cnt = &bar[0];
    int* gen = &bar[1];

    __shared__ float tile[32][33];
    __shared__ __align__(16) int8_t As[128 * 64];
    __shared__ __align__(16) int8_t Bs[128 * 64];

    // ---- phase 1: X->i8 (4 jobs) + W1 transpose/quant (32 jobs) ----
#pragma unroll 1
    for (int k = 0; k < 4; ++k) {
        int g  = (b * 4 + k) * 256 + tid;
        int e0 = g * 4;
        int row = e0 / NIN;
        uint32_t p = 0;
        if (row < N_STEPS) {
            f32x4 v = *(const f32x4*)(x + e0);
#pragma unroll
            for (int q = 0; q < 4; ++q)
                p |= (v[q] > 0.5f ? 1u : 0u) << (8 * q);
        }
        *(uint32_t*)(Xi + e0) = p;
    }
#pragma unroll 1
    for (int k = 0; k < 32; ++k) {
        int tb = b * 32 + k;          // 0..16383
        int c0 = (tb & 255) * 32;
        int r0 = (tb >> 8) * 32;
        int tx = tid & 31;
        int ty = tid >> 5;
        __syncthreads();
#pragma unroll
        for (int i = 0; i < 4; ++i) {
            int r = r0 + ty + i * 8;
            tile[ty + i * 8][tx] = W1[(size_t)r * NHID + (c0 + tx)];
        }
        __syncthreads();
        int lc = tid >> 3;
        int rg = tid & 7;
        uint32_t p = 0;
#pragma unroll
        for (int q = 0; q < 4; ++q) {
            int v = __float2int_rn(tile[rg * 4 + q][lc] * WQ);
            p |= (uint32_t)(v & 0xff) << (8 * q);
        }
        *(uint32_t*)(W1t + (size_t)(c0 + lc) * NIN + r0 + rg * 4) = p;
    }
    gsync(cnt, gen);

    // ---- phase 2: CUR1 = (Xi @ W1t^T)/WQ bf16 + fused Ph partials ----
    {
        const int lane = tid & 63;
        const int wave = tid >> 6;
        const int xc = b & 7;
        const int rr = b >> 3;
        const int bn = (xc * 8 + (rr & 7)) * 128;
        const int bm = (rr >> 3) * 128;
        const int N = NHID, K = NIN;

        const int cc0 = wave * 64 + lane;
        const int r0 = cc0 >> 2, q0 = cc0 & 3;
        const int cc1 = 256 + cc0;
        const int r1 = cc1 >> 2, q1 = cc1 & 3;

        const int8_t* Ag0 = Xi  + (size_t)(bm + r0) * K + q0 * 16;
        const int8_t* Ag1 = Xi  + (size_t)(bm + r1) * K + q1 * 16;
        const int8_t* Bg0 = W1t + (size_t)(bn + r0) * K + q0 * 16;
        const int8_t* Bg1 = W1t + (size_t)(bn + r1) * K + q1 * 16;
        int8_t* lA0 = &As[(wave * 64) * 16];
        int8_t* lA1 = &As[(256 + wave * 64) * 16];
        int8_t* lB0 = &Bs[(wave * 64) * 16];
        int8_t* lB1 = &Bs[(256 + wave * 64) * 16];

        i32x4 acc[4][4];
#pragma unroll
        for (int i = 0; i < 4; ++i)
#pragma unroll
            for (int j = 0; j < 4; ++j)
                acc[i][j] = (i32x4){0, 0, 0, 0};

        const int wr   = wave >> 1;
        const int wc   = wave & 1;
        const int fr   = lane & 15;
        const int kc16 = (lane >> 4) * 16;

        for (int k0 = 0; k0 < K; k0 += 64) {
            gl_lds16(Ag0 + k0, lA0);
            gl_lds16(Ag1 + k0, lA1);
            gl_lds16(Bg0 + k0, lB0);
            gl_lds16(Bg1 + k0, lB1);
            __syncthreads();
            i32x4 a[4], bb[4];
#pragma unroll
            for (int mi = 0; mi < 4; ++mi)
                a[mi] = *(const i32x4*)(&As[(wr * 64 + mi * 16 + fr) * 64 + kc16]);
#pragma unroll
            for (int ni = 0; ni < 4; ++ni)
                bb[ni] = *(const i32x4*)(&Bs[(wc * 64 + ni * 16 + fr) * 64 + kc16]);
#pragma unroll
            for (int mi = 0; mi < 4; ++mi)
#pragma unroll
                for (int ni = 0; ni < 4; ++ni)
                    acc[mi][ni] = __builtin_amdgcn_mfma_i32_16x16x64_i8(
                        a[mi], bb[ni], acc[mi][ni], 0, 0, 0);
            __syncthreads();
        }

        const int q4 = (lane >> 4) * 4;
        const float inv = 1.0f / WQ;
        float ew[4];
#pragma unroll
        for (int q = 0; q < 4; ++q)
            ew[q] = __expf(LIF_LAM * (float)(q4 + q));
#pragma unroll
        for (int mi = 0; mi < 4; ++mi) {
            const int rbase  = bm + wr * 64 + mi * 16;
            const int seg    = rbase >> 4;
            const float wseg = __expf(LIF_LAM * (float)rbase);
#pragma unroll
            for (int ni = 0; ni < 4; ++ni) {
                const int col = bn + wc * 64 + ni * 16 + fr;
                float f[4];
#pragma unroll
                for (int q = 0; q < 4; ++q) {
                    f[q] = (float)acc[mi][ni][q] * inv;
                    int row = rbase + q4 + q;
                    CUR1[(size_t)row * N + col] = __float2bfloat16(f[q]);
                }
                float v = f[0] * ew[0] + f[1] * ew[1] + f[2] * ew[2] + f[3] * ew[3];
                v += __shfl_xor(v, 16);
                v += __shfl_xor(v, 32);
                if (lane < 16)
                    Ph[(size_t)seg * N + col] = v * wseg;
            }
        }
    }
    gsync(cnt, gen);

    // ---- phase 3: hidden first-crossing (4 jobs) + zero CUR2 ----
#pragma unroll 1
    for (int k = 0; k < 4; ++k) {
        int gt  = (b * 4 + k) * 256 + tid;
        int j   = gt & (NHID - 1);
        int seg = gt / NHID;
        float G = 0.f;
        for (int s = 0; s < seg; ++s) G += Ph[(size_t)s * NHID + j];
        float w = __expf(LIF_LAM * (float)(seg * SEGLEN));
        int found = -1;
#pragma unroll
        for (int u = 0; u < SEGLEN; ++u) {
            int t = seg * SEGLEN + u;
            G += __bfloat162float(CUR1[(size_t)t * NHID + j]) * w;
            if (found < 0 && t < N_STEPS && G > LIF_THRG * w) found = t;
            w *= LIF_DINV;
        }
        if (found >= 0) atomicMin(&t1[j], found);
    }
    {
        int gt = b * 256 + tid;
#pragma unroll
        for (int k = 0; k < 4; ++k)
            *(f32x4*)(CUR2 + ((size_t)gt * 4 + (size_t)k * 524288)) =
                (f32x4){0.f, 0.f, 0.f, 0.f};
    }
    gsync(cnt, gen);

    // ---- phase 4: sparse layer-2 gather (run-length batched atomics) ----
    {
        int gt = b * 256 + tid;
        if (gt < 32768) {
            int i4 = (gt & 511) * 4;
            int jb = (gt >> 9) * 128;
            f32x4 acc = (f32x4){0.f, 0.f, 0.f, 0.f};
            int run_t = -1;
#pragma unroll 1
            for (int bb = 0; bb < 128; bb += 16) {
                int   tf[16];
                f32x4 w[16];
#pragma unroll
                for (int u = 0; u < 16; ++u) tf[u] = t1[jb + bb + u];
#pragma unroll
                for (int u = 0; u < 16; ++u)
                    w[u] = *(const f32x4*)(W2 + (size_t)(jb + bb + u) * NIN + i4);
#pragma unroll
                for (int u = 0; u < 16; ++u) {
                    int t = tf[u];
                    if (t >= N_STEPS) continue;
                    if (t != run_t) {
                        if (run_t >= 0) {
                            float* d = &CUR2[(size_t)run_t * NIN + i4];
                            atomicAdd(d + 0, acc[0]); atomicAdd(d + 1, acc[1]);
                            atomicAdd(d + 2, acc[2]); atomicAdd(d + 3, acc[3]);
                        }
                        run_t = t;
                        acc = w[u];
                    } else {
                        acc += w[u];
                    }
                }
            }
            if (run_t >= 0) {
                float* d = &CUR2[(size_t)run_t * NIN + i4];
                atomicAdd(d + 0, acc[0]); atomicAdd(d + 1, acc[1]);
                atomicAdd(d + 2, acc[2]); atomicAdd(d + 3, acc[3]);
            }
        }
    }
    gsync(cnt, gen);

    // ---- phase 5: output first-crossing scan ----
    {
        int i = b * 256 + tid;
        if (i < NIN) {
            float G = 0.f, w = 1.f;
            int found = 0x7FFFFFFF;
#pragma unroll 1
            for (int t = 0; t < N_STEPS; ++t) {
                G += CUR2[(size_t)t * NIN + i] * w;
                if (G > LIF_THRG * w) { found = t; break; }
                w *= LIF_DINV;
            }
            t2[i] = found;
        }
    }
    gsync(cnt, gen);

    // ---- phase 6: write full out (incl. row 0) ----
    {
        int gt = b * 256 + tid;
#pragma unroll 1
        for (int k = 0; k < 4; ++k) {
            int job = gt + k * 131072;
            if (job < N_STEPS * 512) {
                int t  = job >> 9;
                int i4 = (job & 511) * 4;
                f32x4 v;
#pragma unroll
                for (int u = 0; u < 4; ++u)
                    v[u] = (t2[i4 + u] == t) ? 1.0f : 0.0f;
                *(f32x4*)(out + (size_t)t * NIN + i4) = v;
            }
        }
    }
}

// ---------------------------------------------------------------------------
extern "C" void kernel_launch(void* const* d_in, const int* in_sizes, int n_in,
                              void* d_out, int out_size, void* d_ws, size_t ws_size,
                              hipStream_t stream) {
    const float* X  = (const float*)d_in[0];   // [1000, 2048]
    const float* W1 = (const float*)d_in[1];   // [2048, 8192]
    const float* W2 = (const float*)d_in[2];   // [8192, 2048]
    float* out = (float*)d_out;                // [1000, 2048]

    char* ws = (char*)d_ws;
    int8_t*          Xi   = (int8_t*)         (ws);                   //  2 MiB
    int8_t*          W1t  = (int8_t*)         (ws + (2ull   << 20));  // 16 MiB
    __hip_bfloat16*  CUR1 = (__hip_bfloat16*) (ws + (18ull  << 20));  // 16 MiB
    float*           Ph   = (float*)          (ws + (34ull  << 20));  //  2 MiB
    float*           CUR2 = (float*)          (ws + (36ull  << 20));  //  8 MiB
    float*           PART = (float*)          (ws + (44ull  << 20));  //  2 MiB [256][2048]
    float*           PS   = (float*)          (ws + (46ull  << 20));  // .5 MiB [16][8192]
    int*             t1   = (int*)            (ws + (49ull  << 20));  // 32 KiB
    int*             t2   = (int*)            (ws + (49ull  << 20) + 32768);
    int*             flag = (int*)            (ws + (49ull  << 20) + 40960);
    int*             bar  = (int*)            (ws + (49ull  << 20) + 40968);

    // 1) front: 512-block W2 colsum + ballot-ILP rowvec + zero out rows
    //    1..999 + state init (heterogeneous jobs on separate blocks)
    front<<<1280, 256, 0, stream>>>(X, W1, W2, PART, PS, out, flag, bar);
    // 2) decide (t1, flag) + speculative out row 0 from W2 colsum
    tail<<<64, 256, 0, stream>>>(PS, PART, t1, flag, out);
    // 3) generic fallback (single gated dispatch; dead when flag==0,
    //    rewrites the full output when flag!=0)
    mega<<<NBLK, 256, 0, stream>>>(X, W1, W2, Xi, W1t, CUR1, Ph, CUR2, t1, t2,
                                   out, flag, bar);
}

// Round 15
// 23.573 us; speedup vs baseline: 1.0937x; 1.0937x over previous
//
#include <hip/hip_runtime.h>
#include <hip/hip_bf16.h>
#include <stdint.h>

// Problem constants (fixed by reference)
#define N_STEPS 1000
#define NIN     2048
#define NHID    8192
#define M_PAD   1024

// LIF: TAU_REF/DT = 2000 > N_STEPS -> each neuron fires AT MOST ONCE; before
// first fire the recurrence is linear:
//   fire at first t with G(t) > 0.02*e^{5e-5 t}, G(t)=sum_{u<=t} c(u)e^{5e-5 u}
// At t=0: fire iff cur(0) > 0.02. For this data cur1(0) ~ 100 >> 0.02, so ALL
// hidden neurons fire at t=0 (flag==0). Then S1 = e_0 (x) ones, layer 2
// collapses to a column-sum of W2, and (G2 constant, threshold rising) the
// output fires at t=0 or never -> out rows 1..999 are all zero.
//
// R10 lesson: heterogeneous jobs on DIFFERENT blocks (don't serialize
// BW-bound behind latency-bound work in one block).
// R12 lesson: persistent-kernel grid barriers on a BW-bound live path
// collapse bandwidth; keep the live path as plain dispatches.
// R13 lesson: ballot-mask + 4-deep ILP kills the rowvec latency chain.
// R14 lesson: 256-block colsum (1/CU) already saturates BW; 512 regresses.
#define LIF_DINV   1.0000500012500208f   // e^{+DT/TAU_MEM}
#define LIF_LAM    5.0e-5f               // DT/TAU_MEM
#define LIF_THRG   0.02f                 // THR/SCALE

#define SEGS    64
#define SEGLEN  16
#define WQ      127.0f   // W1 i8 quant scale (fallback GEMM)
#define ISLICES 16       // rowvec i-slices (128 input rows each)
#define NBLK    512      // mega grid (2 blocks/CU on 256 CUs -> co-resident)

typedef short  bf16x8 __attribute__((ext_vector_type(8)));
typedef float  f32x4  __attribute__((ext_vector_type(4)));
typedef int    i32x4  __attribute__((ext_vector_type(4)));

typedef const __attribute__((address_space(1))) void gvoid_t;
typedef       __attribute__((address_space(3))) void lvoid_t;

__device__ __forceinline__ void gl_lds16(const void* g, void* l) {
    __builtin_amdgcn_global_load_lds((gvoid_t*)g, (lvoid_t*)l, 16, 0, 0);
}

// device-scope grid barrier (fallback path only; 512 blocks co-resident by
// __launch_bounds__(256,2) x 256 CUs)
__device__ __forceinline__ void gsync(int* cnt, int* gen) {
    __syncthreads();
    if (threadIdx.x == 0) {
        __threadfence();
        int g = __hip_atomic_load(gen, __ATOMIC_RELAXED, __HIP_MEMORY_SCOPE_AGENT);
        int a = __hip_atomic_fetch_add(cnt, 1, __ATOMIC_ACQ_REL, __HIP_MEMORY_SCOPE_AGENT);
        if (a == NBLK - 1) {
            __hip_atomic_store(cnt, 0, __ATOMIC_RELAXED, __HIP_MEMORY_SCOPE_AGENT);
            __hip_atomic_fetch_add(gen, 1, __ATOMIC_RELEASE, __HIP_MEMORY_SCOPE_AGENT);
        } else {
            while (__hip_atomic_load(gen, __ATOMIC_ACQUIRE, __HIP_MEMORY_SCOPE_AGENT) == g)
                __builtin_amdgcn_s_sleep(8);
        }
        __threadfence();
    }
    __syncthreads();
}

// ========================== LIVE PATH =======================================

// front (1024 blocks) — heterogeneous jobs on DIFFERENT blocks:
//   blocks   0..255 : PART[slice][i] = sum of 64 W2 rows  (colsum stage 1)
//   blocks 256..767 : PS[is][j] = sum_{i active in slice} W1[i][j]
//                     (ballot mask + 4-deep ILP bit-scan: only ~13 active
//                      rows are touched; 4 loads in flight kills the ~10us
//                      serial-latency chain of the naive 128-iter loop)
//   blocks 768..1023: out rows 1..999 = 0
//   block 0 thread 0: init flag + barrier state (replay-safe)
__global__ void front(const float* __restrict__ x, const float* __restrict__ W1,
                      const float* __restrict__ W2,
                      float* __restrict__ PART, float* __restrict__ PS,
                      float* __restrict__ out, int* __restrict__ flag,
                      int* __restrict__ bar) {
    const int bid = blockIdx.x;
    const int tid = threadIdx.x;
    if (bid == 0 && tid == 0) { *flag = 0; bar[0] = 0; bar[1] = 0; }
    if (bid < 256) {
        const int slice = bid >> 1;                       // 0..127
        const int col4  = ((bid & 1) * 256 + tid) * 4;
        const float* base = W2 + (size_t)slice * 64 * NIN + col4;
        f32x4 s = (f32x4){0.f, 0.f, 0.f, 0.f};
#pragma unroll 16
        for (int u = 0; u < 64; ++u)
            s += *(const f32x4*)(base + (size_t)u * NIN);  // 1KB/wave, deep ILP
        *(f32x4*)(PART + (size_t)slice * NIN + col4) = s;
    } else if (bid < 768) {
        const int rb   = bid - 256;
        const int jc   = rb & 31;                          // 32 j-chunks
        const int is   = rb >> 5;                          // 16 i-slices
        const int j    = jc * 256 + tid;
        const int lane = tid & 63;
        const int ib   = is * 128;
        // wave-uniform 128-bit activity mask (two coalesced 256B x-reads)
        uint64_t m0 = __ballot(x[ib + lane] > 0.5f);        // rows ib..ib+63
        uint64_t m1 = __ballot(x[ib + 64 + lane] > 0.5f);   // rows +64..+127
        float s0 = 0.f, s1 = 0.f, s2 = 0.f, s3 = 0.f;
#pragma unroll 1
        for (int half = 0; half < 2; ++half) {
            uint64_t m   = half ? m1 : m0;
            const int rb0 = ib + half * 64;
#pragma unroll 1
            while (m) {
                int r0 = __ffsll((unsigned long long)m) - 1; m &= m - 1;
                int r1 = -1, r2 = -1, r3 = -1;
                if (m) { r1 = __ffsll((unsigned long long)m) - 1; m &= m - 1; }
                if (m) { r2 = __ffsll((unsigned long long)m) - 1; m &= m - 1; }
                if (m) { r3 = __ffsll((unsigned long long)m) - 1; m &= m - 1; }
                // 4 independent coalesced row loads in flight
                s0 += W1[(size_t)(rb0 + r0) * NHID + j];
                if (r1 >= 0) s1 += W1[(size_t)(rb0 + r1) * NHID + j];
                if (r2 >= 0) s2 += W1[(size_t)(rb0 + r2) * NHID + j];
                if (r3 >= 0) s3 += W1[(size_t)(rb0 + r3) * NHID + j];
            }
        }
        PS[(size_t)is * NHID + j] = (s0 + s1) + (s2 + s3);
    } else {
        const int zb = bid - 768;                          // 0..255
#pragma unroll
        for (int k = 0; k < 8; ++k) {
            int job = zb * 256 + tid + k * 65536;          // rows 1..999
            if (job < 999 * 512) {
                int row  = 1 + (job >> 9);
                int col4 = (job & 511) * 4;
                *(f32x4*)(out + (size_t)row * NIN + col4) = (f32x4){0.f, 0.f, 0.f, 0.f};
            }
        }
    }
}

// tail (64 blocks):
//   blocks  0..31: decide — t1[j] = 0 if fired at t=0 else INT_MAX; flag
//   blocks 32..63: out[0][i] = (colsum W2 > 0.02) speculatively (mega, which
//                  runs after, rewrites the full output whenever flag != 0)
__global__ void tail(const float* __restrict__ PS, const float* __restrict__ PART,
                     int* __restrict__ t1, int* __restrict__ flag,
                     float* __restrict__ out) {
    const int bid = blockIdx.x;
    const int tid = threadIdx.x;
    if (bid < 32) {
        int j = bid * 256 + tid;
        float s = 0.f;
#pragma unroll
        for (int u = 0; u < ISLICES; ++u) s += PS[(size_t)u * NHID + j];
        bool fire = s > LIF_THRG;
        t1[j] = fire ? 0 : 0x7FFFFFFF;
        if (!fire) *flag = 1;    // benign race, same value
    } else {
        __shared__ float red[4][64];
        const int lc   = tid & 63;
        const int part = tid >> 6;                          // 0..3
        const int col  = (bid - 32) * 64 + lc;              // 32 blocks x 64 cols
        float s = 0.f;
#pragma unroll 8
        for (int u = 0; u < 32; ++u)
            s += PART[(size_t)(part * 32 + u) * NIN + col]; // 128 slices total
        red[part][lc] = s;
        __syncthreads();
        if (tid < 64) {
            float tot = red[0][lc] + red[1][lc] + red[2][lc] + red[3][lc];
            out[col] = (tot > LIF_THRG) ? 1.0f : 0.0f;
        }
    }
}

// ================= GATED FALLBACK: ONE KERNEL, GRID-BARRIER =================
// Dead under bench data (flag==0 -> return before any barrier). Generic path:
// prep -> gemm -> seg_cross/zero -> gather -> out_scan -> write full out.
__launch_bounds__(256, 2)
__global__ void mega(const float* __restrict__ x, const float* __restrict__ W1,
                     const float* __restrict__ W2,
                     int8_t* __restrict__ Xi, int8_t* __restrict__ W1t,
                     __hip_bfloat16* __restrict__ CUR1, float* __restrict__ Ph,
                     float* __restrict__ CUR2, int* __restrict__ t1,
                     int* __restrict__ t2, float* __restrict__ out,
                     const int* __restrict__ flag, int* __restrict__ bar) {
    if (*flag == 0) return;
    const int b   = blockIdx.x;     // 0..511
    const int tid = threadIdx.x;
    int* cnt = &bar[0];
    int* gen = &bar[1];

    __shared__ float tile[32][33];
    __shared__ __align__(16) int8_t As[128 * 64];
    __shared__ __align__(16) int8_t Bs[128 * 64];

    // ---- phase 1: X->i8 (4 jobs) + W1 transpose/quant (32 jobs) ----
#pragma unroll 1
    for (int k = 0; k < 4; ++k) {
        int g  = (b * 4 + k) * 256 + tid;
        int e0 = g * 4;
        int row = e0 / NIN;
        uint32_t p = 0;
        if (row < N_STEPS) {
            f32x4 v = *(const f32x4*)(x + e0);
#pragma unroll
            for (int q = 0; q < 4; ++q)
                p |= (v[q] > 0.5f ? 1u : 0u) << (8 * q);
        }
        *(uint32_t*)(Xi + e0) = p;
    }
#pragma unroll 1
    for (int k = 0; k < 32; ++k) {
        int tb = b * 32 + k;          // 0..16383
        int c0 = (tb & 255) * 32;
        int r0 = (tb >> 8) * 32;
        int tx = tid & 31;
        int ty = tid >> 5;
        __syncthreads();
#pragma unroll
        for (int i = 0; i < 4; ++i) {
            int r = r0 + ty + i * 8;
            tile[ty + i * 8][tx] = W1[(size_t)r * NHID + (c0 + tx)];
        }
        __syncthreads();
        int lc = tid >> 3;
        int rg = tid & 7;
        uint32_t p = 0;
#pragma unroll
        for (int q = 0; q < 4; ++q) {
            int v = __float2int_rn(tile[rg * 4 + q][lc] * WQ);
            p |= (uint32_t)(v & 0xff) << (8 * q);
        }
        *(uint32_t*)(W1t + (size_t)(c0 + lc) * NIN + r0 + rg * 4) = p;
    }
    gsync(cnt, gen);

    // ---- phase 2: CUR1 = (Xi @ W1t^T)/WQ bf16 + fused Ph partials ----
    {
        const int lane = tid & 63;
        const int wave = tid >> 6;
        const int xc = b & 7;
        const int rr = b >> 3;
        const int bn = (xc * 8 + (rr & 7)) * 128;
        const int bm = (rr >> 3) * 128;
        const int N = NHID, K = NIN;

        const int cc0 = wave * 64 + lane;
        const int r0 = cc0 >> 2, q0 = cc0 & 3;
        const int cc1 = 256 + cc0;
        const int r1 = cc1 >> 2, q1 = cc1 & 3;

        const int8_t* Ag0 = Xi  + (size_t)(bm + r0) * K + q0 * 16;
        const int8_t* Ag1 = Xi  + (size_t)(bm + r1) * K + q1 * 16;
        const int8_t* Bg0 = W1t + (size_t)(bn + r0) * K + q0 * 16;
        const int8_t* Bg1 = W1t + (size_t)(bn + r1) * K + q1 * 16;
        int8_t* lA0 = &As[(wave * 64) * 16];
        int8_t* lA1 = &As[(256 + wave * 64) * 16];
        int8_t* lB0 = &Bs[(wave * 64) * 16];
        int8_t* lB1 = &Bs[(256 + wave * 64) * 16];

        i32x4 acc[4][4];
#pragma unroll
        for (int i = 0; i < 4; ++i)
#pragma unroll
            for (int j = 0; j < 4; ++j)
                acc[i][j] = (i32x4){0, 0, 0, 0};

        const int wr   = wave >> 1;
        const int wc   = wave & 1;
        const int fr   = lane & 15;
        const int kc16 = (lane >> 4) * 16;

        for (int k0 = 0; k0 < K; k0 += 64) {
            gl_lds16(Ag0 + k0, lA0);
            gl_lds16(Ag1 + k0, lA1);
            gl_lds16(Bg0 + k0, lB0);
            gl_lds16(Bg1 + k0, lB1);
            __syncthreads();
            i32x4 a[4], bb[4];
#pragma unroll
            for (int mi = 0; mi < 4; ++mi)
                a[mi] = *(const i32x4*)(&As[(wr * 64 + mi * 16 + fr) * 64 + kc16]);
#pragma unroll
            for (int ni = 0; ni < 4; ++ni)
                bb[ni] = *(const i32x4*)(&Bs[(wc * 64 + ni * 16 + fr) * 64 + kc16]);
#pragma unroll
            for (int mi = 0; mi < 4; ++mi)
#pragma unroll
                for (int ni = 0; ni < 4; ++ni)
                    acc[mi][ni] = __builtin_amdgcn_mfma_i32_16x16x64_i8(
                        a[mi], bb[ni], acc[mi][ni], 0, 0, 0);
            __syncthreads();
        }

        const int q4 = (lane >> 4) * 4;
        const float inv = 1.0f / WQ;
        float ew[4];
#pragma unroll
        for (int q = 0; q < 4; ++q)
            ew[q] = __expf(LIF_LAM * (float)(q4 + q));
#pragma unroll
        for (int mi = 0; mi < 4; ++mi) {
            const int rbase  = bm + wr * 64 + mi * 16;
            const int seg    = rbase >> 4;
            const float wseg = __expf(LIF_LAM * (float)rbase);
#pragma unroll
            for (int ni = 0; ni < 4; ++ni) {
                const int col = bn + wc * 64 + ni * 16 + fr;
                float f[4];
#pragma unroll
                for (int q = 0; q < 4; ++q) {
                    f[q] = (float)acc[mi][ni][q] * inv;
                    int row = rbase + q4 + q;
                    CUR1[(size_t)row * N + col] = __float2bfloat16(f[q]);
                }
                float v = f[0] * ew[0] + f[1] * ew[1] + f[2] * ew[2] + f[3] * ew[3];
                v += __shfl_xor(v, 16);
                v += __shfl_xor(v, 32);
                if (lane < 16)
                    Ph[(size_t)seg * N + col] = v * wseg;
            }
        }
    }
    gsync(cnt, gen);

    // ---- phase 3: hidden first-crossing (4 jobs) + zero CUR2 ----
#pragma unroll 1
    for (int k = 0; k < 4; ++k) {
        int gt  = (b * 4 + k) * 256 + tid;
        int j   = gt & (NHID - 1);
        int seg = gt / NHID;
        float G = 0.f;
        for (int s = 0; s < seg; ++s) G += Ph[(size_t)s * NHID + j];
        float w = __expf(LIF_LAM * (float)(seg * SEGLEN));
        int found = -1;
#pragma unroll
        for (int u = 0; u < SEGLEN; ++u) {
            int t = seg * SEGLEN + u;
            G += __bfloat162float(CUR1[(size_t)t * NHID + j]) * w;
            if (found < 0 && t < N_STEPS && G > LIF_THRG * w) found = t;
            w *= LIF_DINV;
        }
        if (found >= 0) atomicMin(&t1[j], found);
    }
    {
        int gt = b * 256 + tid;
#pragma unroll
        for (int k = 0; k < 4; ++k)
            *(f32x4*)(CUR2 + ((size_t)gt * 4 + (size_t)k * 524288)) =
                (f32x4){0.f, 0.f, 0.f, 0.f};
    }
    gsync(cnt, gen);

    // ---- phase 4: sparse layer-2 gather (run-length batched atomics) ----
    {
        int gt = b * 256 + tid;
        if (gt < 32768) {
            int i4 = (gt & 511) * 4;
            int jb = (gt >> 9) * 128;
            f32x4 acc = (f32x4){0.f, 0.f, 0.f, 0.f};
            int run_t = -1;
#pragma unroll 1
            for (int bb = 0; bb < 128; bb += 16) {
                int   tf[16];
                f32x4 w[16];
#pragma unroll
                for (int u = 0; u < 16; ++u) tf[u] = t1[jb + bb + u];
#pragma unroll
                for (int u = 0; u < 16; ++u)
                    w[u] = *(const f32x4*)(W2 + (size_t)(jb + bb + u) * NIN + i4);
#pragma unroll
                for (int u = 0; u < 16; ++u) {
                    int t = tf[u];
                    if (t >= N_STEPS) continue;
                    if (t != run_t) {
                        if (run_t >= 0) {
                            float* d = &CUR2[(size_t)run_t * NIN + i4];
                            atomicAdd(d + 0, acc[0]); atomicAdd(d + 1, acc[1]);
                            atomicAdd(d + 2, acc[2]); atomicAdd(d + 3, acc[3]);
                        }
                        run_t = t;
                        acc = w[u];
                    } else {
                        acc += w[u];
                    }
                }
            }
            if (run_t >= 0) {
                float* d = &CUR2[(size_t)run_t * NIN + i4];
                atomicAdd(d + 0, acc[0]); atomicAdd(d + 1, acc[1]);
                atomicAdd(d + 2, acc[2]); atomicAdd(d + 3, acc[3]);
            }
        }
    }
    gsync(cnt, gen);

    // ---- phase 5: output first-crossing scan ----
    {
        int i = b * 256 + tid;
        if (i < NIN) {
            float G = 0.f, w = 1.f;
            int found = 0x7FFFFFFF;
#pragma unroll 1
            for (int t = 0; t < N_STEPS; ++t) {
                G += CUR2[(size_t)t * NIN + i] * w;
                if (G > LIF_THRG * w) { found = t; break; }
                w *= LIF_DINV;
            }
            t2[i] = found;
        }
    }
    gsync(cnt, gen);

    // ---- phase 6: write full out (incl. row 0) ----
    {
        int gt = b * 256 + tid;
#pragma unroll 1
        for (int k = 0; k < 4; ++k) {
            int job = gt + k * 131072;
            if (job < N_STEPS * 512) {
                int t  = job >> 9;
                int i4 = (job & 511) * 4;
                f32x4 v;
#pragma unroll
                for (int u = 0; u < 4; ++u)
                    v[u] = (t2[i4 + u] == t) ? 1.0f : 0.0f;
                *(f32x4*)(out + (size_t)t * NIN + i4) = v;
            }
        }
    }
}

// ---------------------------------------------------------------------------
extern "C" void kernel_launch(void* const* d_in, const int* in_sizes, int n_in,
                              void* d_out, int out_size, void* d_ws, size_t ws_size,
                              hipStream_t stream) {
    const float* X  = (const float*)d_in[0];   // [1000, 2048]
    const float* W1 = (const float*)d_in[1];   // [2048, 8192]
    const float* W2 = (const float*)d_in[2];   // [8192, 2048]
    float* out = (float*)d_out;                // [1000, 2048]

    char* ws = (char*)d_ws;
    int8_t*          Xi   = (int8_t*)         (ws);                   //  2 MiB
    int8_t*          W1t  = (int8_t*)         (ws + (2ull   << 20));  // 16 MiB
    __hip_bfloat16*  CUR1 = (__hip_bfloat16*) (ws + (18ull  << 20));  // 16 MiB
    float*           Ph   = (float*)          (ws + (34ull  << 20));  //  2 MiB
    float*           CUR2 = (float*)          (ws + (36ull  << 20));  //  8 MiB
    float*           PART = (float*)          (ws + (44ull  << 20));  //  1 MiB [128][2048]
    float*           PS   = (float*)          (ws + (46ull  << 20));  // .5 MiB [16][8192]
    int*             t1   = (int*)            (ws + (49ull  << 20));  // 32 KiB
    int*             t2   = (int*)            (ws + (49ull  << 20) + 32768);
    int*             flag = (int*)            (ws + (49ull  << 20) + 40960);
    int*             bar  = (int*)            (ws + (49ull  << 20) + 40968);

    // 1) front: W2 colsum partials + ballot-ILP rowvec + zero out rows
    //    1..999 + state init (heterogeneous jobs on separate blocks)
    front<<<1024, 256, 0, stream>>>(X, W1, W2, PART, PS, out, flag, bar);
    // 2) decide (t1, flag) + speculative out row 0 from W2 colsum
    tail<<<64, 256, 0, stream>>>(PS, PART, t1, flag, out);
    // 3) generic fallback (single gated dispatch; dead when flag==0,
    //    rewrites the full output when flag!=0)
    mega<<<NBLK, 256, 0, stream>>>(X, W1, W2, Xi, W1t, CUR1, Ph, CUR2, t1, t2,
                                   out, flag, bar);
}